// Round 2
// baseline (269.936 us; speedup 1.0000x reference)
//
#include <hip/hip_runtime.h>
#include <hip/hip_bf16.h>
#include <stdint.h>

using bf16 = __hip_bfloat16;

typedef __attribute__((ext_vector_type(8))) short short8;
typedef __attribute__((ext_vector_type(4))) float float4v;

namespace {
constexpr int kL  = 4096;
constexpr int kD  = 384;
constexpr int kGW = 64;
constexpr int kM  = 32768;
constexpr int kAP = 392;   // padded agg LDS stride (bf16): 784 B/row -> 2-way (free) banks

constexpr size_t nValue = (size_t)kM * kD;
constexpr size_t nW     = (size_t)kD * kD;
constexpr size_t nWcat  = (size_t)96 * kD;   // 96x384 (transposed cat weight)

// workspace offsets (bytes)
constexpr size_t oWvt  = 0;                                    // bf16 Wv^T [384][384]
constexpr size_t oWot  = oWvt  + nW * 2;                       // bf16 Wo^T [384][384]
constexpr size_t oWch  = oWot  + nW * 2;                       // bf16 Wcat^T hi [96][384]
constexpr size_t oWcl  = oWch  + nWcat * 2;                    // bf16 Wcat^T lo [96][384]
constexpr size_t oBcat = oWcl  + nWcat * 2;                    // f32 [96]
constexpr size_t oVB   = (oBcat + 96 * 4 + 255) & ~size_t(255);// bf16 v [kM][384]
constexpr size_t oProj = oVB   + nValue * 2;                   // f32 [kM][96]
}

__device__ __forceinline__ void load_lds_16(const void* g, void* l) {
  __builtin_amdgcn_global_load_lds((const __attribute__((address_space(1))) void*)g,
                                   (__attribute__((address_space(3))) void*)l,
                                   16, 0, 0);
}

__device__ __forceinline__ short bf16bits(float f) {
  bf16 h = __float2bfloat16(f);
  return *reinterpret_cast<short*>(&h);
}

__device__ __forceinline__ float bf16raw2f(unsigned short u) {
  union { unsigned int i; float f; } c;
  c.i = ((unsigned int)u) << 16;
  return c.f;
}

// -------------------------------------------------------------------------
// prep (weights only): Wv^T, Wo^T as bf16; Wcat^T split into hi/lo bf16 so
// the proj GEMM can run on MFMA with f32-level accuracy (err ~2^-17 rel).
// -------------------------------------------------------------------------
__global__ void prep_kernel(const float* __restrict__ Wv,
                            const float* __restrict__ Wo,
                            const float* __restrict__ Woff,
                            const float* __restrict__ Wwt,
                            const float* __restrict__ boff,
                            const float* __restrict__ bwt,
                            bf16* __restrict__ Wvt, bf16* __restrict__ Wot,
                            bf16* __restrict__ Wch, bf16* __restrict__ Wcl,
                            float* __restrict__ bcat)
{
  size_t i = (size_t)blockIdx.x * 256 + threadIdx.x;
  if (i < nW) {
    const int n = (int)(i / kD), k = (int)(i % kD);
    Wvt[i] = __float2bfloat16(Wv[(size_t)k * kD + n]);
    return;
  }
  i -= nW;
  if (i < nW) {
    const int n = (int)(i / kD), k = (int)(i % kD);
    Wot[i] = __float2bfloat16(Wo[(size_t)k * kD + n]);
    return;
  }
  i -= nW;
  if (i < nWcat) {
    const int n = (int)(i / kD), k = (int)(i % kD);
    const float val = (n < 64) ? Woff[(size_t)k * 64 + n] : Wwt[(size_t)k * 32 + (n - 64)];
    const bf16 h = __float2bfloat16(val);
    Wch[i] = h;
    Wcl[i] = __float2bfloat16(val - __bfloat162float(h));  // exact residual, then rounded
    return;
  }
  i -= nWcat;
  if (i < 96) bcat[i] = (i < 64) ? boff[i] : bwt[i - 64];
}

// -------------------------------------------------------------------------
// v GEMM body (dbuf 2-phase): vB[M,384] = value @ Wv + bv, bf16 out.
// 128x128 tile, BK=32, 4 waves. Next tile's loads issue BEFORE current
// tile's MFMA; the single __syncthreads() per step (vmcnt0+lgkm drain)
// lands the prefetch -> one compute-phase of HBM latency hiding.
// -------------------------------------------------------------------------
__device__ __forceinline__
void vgemm_body(char* smem, int bid,
                const float* __restrict__ A, const bf16* __restrict__ Bt,
                const float* __restrict__ bias, bf16* __restrict__ Cout)
{
  bf16* sA = (bf16*)smem;              // [2][128*32] bf16, 8192 B per buf
  bf16* sB = (bf16*)(smem + 16384);    // [2][128*32]
  const int tid  = threadIdx.x;
  const int lane = tid & 63;
  const int wave = tid >> 6;
  const int bm = bid / 3, bn = bid % 3;
  const int m0 = bm * 128, n0 = bn * 128;
  const int wm = (wave >> 1) * 64, wn = (wave & 1) * 64;
  const int r16 = lane & 15, quad = lane >> 4;

  float4v acc[4][4];
  #pragma unroll
  for (int i = 0; i < 4; ++i)
    #pragma unroll
    for (int j = 0; j < 4; ++j) acc[i][j] = (float4v){0.f, 0.f, 0.f, 0.f};

  const int c0 = tid, c1 = tid + 256;
  const int rA0 = c0 >> 2, cA0 = c0 & 3;
  const int rA1 = c1 >> 2, cA1 = c1 & 3;

  float4 f00, f01, f10, f11;

  // prologue: stage kt=0 into buf 0
  {
    const float* s0 = A + (size_t)(m0 + rA0) * kD + cA0 * 8;
    f00 = *(const float4*)s0; f01 = *(const float4*)(s0 + 4);
    const float* s1 = A + (size_t)(m0 + rA1) * kD + cA1 * 8;
    f10 = *(const float4*)s1; f11 = *(const float4*)(s1 + 4);
    load_lds_16(Bt + (size_t)(n0 + rA0) * kD + cA0 * 8, (char*)sB + c0 * 16);
    load_lds_16(Bt + (size_t)(n0 + rA1) * kD + cA1 * 8, (char*)sB + c1 * 16);
    short8 hx;
    hx[0]=bf16bits(f00.x); hx[1]=bf16bits(f00.y); hx[2]=bf16bits(f00.z); hx[3]=bf16bits(f00.w);
    hx[4]=bf16bits(f01.x); hx[5]=bf16bits(f01.y); hx[6]=bf16bits(f01.z); hx[7]=bf16bits(f01.w);
    *(short8*)((char*)sA + c0 * 16) = hx;
    hx[0]=bf16bits(f10.x); hx[1]=bf16bits(f10.y); hx[2]=bf16bits(f10.z); hx[3]=bf16bits(f10.w);
    hx[4]=bf16bits(f11.x); hx[5]=bf16bits(f11.y); hx[6]=bf16bits(f11.z); hx[7]=bf16bits(f11.w);
    *(short8*)((char*)sA + c1 * 16) = hx;
  }
  __syncthreads();

  for (int kt = 0; kt < 12; ++kt) {
    const int cur = kt & 1, nxt = cur ^ 1;
    if (kt < 11) {
      const int k0n = (kt + 1) * 32;
      const float* s0 = A + (size_t)(m0 + rA0) * kD + k0n + cA0 * 8;
      f00 = *(const float4*)s0; f01 = *(const float4*)(s0 + 4);
      const float* s1 = A + (size_t)(m0 + rA1) * kD + k0n + cA1 * 8;
      f10 = *(const float4*)s1; f11 = *(const float4*)(s1 + 4);
      load_lds_16(Bt + (size_t)(n0 + rA0) * kD + k0n + cA0 * 8, (char*)sB + nxt * 8192 + c0 * 16);
      load_lds_16(Bt + (size_t)(n0 + rA1) * kD + k0n + cA1 * 8, (char*)sB + nxt * 8192 + c1 * 16);
    }
    const bf16* sAc = (const bf16*)((char*)sA + cur * 8192);
    const bf16* sBc = (const bf16*)((char*)sB + cur * 8192);
    short8 av[4], bv[4];
    #pragma unroll
    for (int i = 0; i < 4; ++i)
      av[i] = *(const short8*)(sAc + (wm + i * 16 + r16) * 32 + quad * 8);
    #pragma unroll
    for (int j = 0; j < 4; ++j)
      bv[j] = *(const short8*)(sBc + (wn + j * 16 + r16) * 32 + quad * 8);
    #pragma unroll
    for (int i = 0; i < 4; ++i)
      #pragma unroll
      for (int j = 0; j < 4; ++j)
        acc[i][j] = __builtin_amdgcn_mfma_f32_16x16x32_bf16(av[i], bv[j], acc[i][j], 0, 0, 0);
    if (kt < 11) {
      short8 hx;
      hx[0]=bf16bits(f00.x); hx[1]=bf16bits(f00.y); hx[2]=bf16bits(f00.z); hx[3]=bf16bits(f00.w);
      hx[4]=bf16bits(f01.x); hx[5]=bf16bits(f01.y); hx[6]=bf16bits(f01.z); hx[7]=bf16bits(f01.w);
      *(short8*)((char*)sA + nxt * 8192 + c0 * 16) = hx;
      hx[0]=bf16bits(f10.x); hx[1]=bf16bits(f10.y); hx[2]=bf16bits(f10.z); hx[3]=bf16bits(f10.w);
      hx[4]=bf16bits(f11.x); hx[5]=bf16bits(f11.y); hx[6]=bf16bits(f11.z); hx[7]=bf16bits(f11.w);
      *(short8*)((char*)sA + nxt * 8192 + c1 * 16) = hx;
      __syncthreads();
    }
  }

  #pragma unroll
  for (int j = 0; j < 4; ++j) {
    const int col = n0 + wn + j * 16 + r16;
    const float bj = bias[col];
    #pragma unroll
    for (int i = 0; i < 4; ++i) {
      const int mbase = m0 + wm + i * 16 + quad * 4;
      #pragma unroll
      for (int r = 0; r < 4; ++r)
        Cout[(size_t)(mbase + r) * kD + col] = __float2bfloat16(acc[i][j][r] + bj);
    }
  }
}

// -------------------------------------------------------------------------
// proj GEMM body (dbuf 2-phase, split-bf16 MFMA): proj[M,96] = Q @ Wcat + bcat.
// acc = Ahi*Bhi + Ahi*Blo + Alo*Bhi  (f32-level accuracy).
// -------------------------------------------------------------------------
__device__ __forceinline__
void proj_body(char* smem, int bid,
               const float* __restrict__ Q,
               const bf16* __restrict__ WhT, const bf16* __restrict__ WlT,
               const float* __restrict__ bc, float* __restrict__ proj)
{
  bf16* sAh  = (bf16*)smem;             // [2][128*32], 8192 B/buf
  bf16* sAl  = (bf16*)(smem + 16384);
  char* sBhB = smem + 32768;            // [2][96*32*2B], 6144 B/buf
  char* sBlB = smem + 45056;            // total 57344
  const int tid  = threadIdx.x;
  const int lane = tid & 63;
  const int wave = tid >> 6;
  const int m0 = bid * 128;
  const int wm = (wave >> 1) * 64, wn = (wave & 1) * 48;
  const int r16 = lane & 15, quad = lane >> 4;

  float4v acc[4][3];
  #pragma unroll
  for (int i = 0; i < 4; ++i)
    #pragma unroll
    for (int j = 0; j < 3; ++j) acc[i][j] = (float4v){0.f, 0.f, 0.f, 0.f};

  const int c0 = tid, c1 = tid + 256;
  const int rA0 = c0 >> 2, cA0 = c0 & 3;
  const int rA1 = c1 >> 2, cA1 = c1 & 3;
  const int cB1 = tid + 256;            // 256..511 (hi if <384 else lo-384)
  const int cB2 = tid + 128;            // lo chunks 128..383

  float4 f00, f01, f10, f11;

  auto stageB = [&](int k0, int buf) {
    load_lds_16(WhT + (size_t)(tid >> 2) * kD + k0 + (tid & 3) * 8, sBhB + buf * 6144 + tid * 16);
    if (cB1 < 384) {
      load_lds_16(WhT + (size_t)(cB1 >> 2) * kD + k0 + (cB1 & 3) * 8, sBhB + buf * 6144 + cB1 * 16);
    } else {
      const int cc = cB1 - 384;
      load_lds_16(WlT + (size_t)(cc >> 2) * kD + k0 + (cc & 3) * 8, sBlB + buf * 6144 + cc * 16);
    }
    load_lds_16(WlT + (size_t)(cB2 >> 2) * kD + k0 + (cB2 & 3) * 8, sBlB + buf * 6144 + cB2 * 16);
  };
  auto castA = [&](int buf) {
    const float fv0[8] = {f00.x, f00.y, f00.z, f00.w, f01.x, f01.y, f01.z, f01.w};
    const float fv1[8] = {f10.x, f10.y, f10.z, f10.w, f11.x, f11.y, f11.z, f11.w};
    short8 hx, lx;
    #pragma unroll
    for (int q = 0; q < 8; ++q) {
      const bf16 h = __float2bfloat16(fv0[q]);
      hx[q] = *reinterpret_cast<const short*>(&h);
      const bf16 lo = __float2bfloat16(fv0[q] - __bfloat162float(h));
      lx[q] = *reinterpret_cast<const short*>(&lo);
    }
    *(short8*)((char*)sAh + buf * 8192 + c0 * 16) = hx;
    *(short8*)((char*)sAl + buf * 8192 + c0 * 16) = lx;
    #pragma unroll
    for (int q = 0; q < 8; ++q) {
      const bf16 h = __float2bfloat16(fv1[q]);
      hx[q] = *reinterpret_cast<const short*>(&h);
      const bf16 lo = __float2bfloat16(fv1[q] - __bfloat162float(h));
      lx[q] = *reinterpret_cast<const short*>(&lo);
    }
    *(short8*)((char*)sAh + buf * 8192 + c1 * 16) = hx;
    *(short8*)((char*)sAl + buf * 8192 + c1 * 16) = lx;
  };
  auto loadA = [&](int k0) {
    const float* s0 = Q + (size_t)(m0 + rA0) * kD + k0 + cA0 * 8;
    f00 = *(const float4*)s0; f01 = *(const float4*)(s0 + 4);
    const float* s1 = Q + (size_t)(m0 + rA1) * kD + k0 + cA1 * 8;
    f10 = *(const float4*)s1; f11 = *(const float4*)(s1 + 4);
  };

  loadA(0);
  stageB(0, 0);
  castA(0);
  __syncthreads();

  for (int kt = 0; kt < 12; ++kt) {
    const int cur = kt & 1, nxt = cur ^ 1;
    if (kt < 11) {
      loadA((kt + 1) * 32);
      stageB((kt + 1) * 32, nxt);
    }
    const bf16* sAhc = (const bf16*)((char*)sAh + cur * 8192);
    const bf16* sAlc = (const bf16*)((char*)sAl + cur * 8192);
    const bf16* sBhc = (const bf16*)(sBhB + cur * 6144);
    const bf16* sBlc = (const bf16*)(sBlB + cur * 6144);
    short8 avh[4], avl[4];
    #pragma unroll
    for (int i = 0; i < 4; ++i) {
      avh[i] = *(const short8*)(sAhc + (wm + i * 16 + r16) * 32 + quad * 8);
      avl[i] = *(const short8*)(sAlc + (wm + i * 16 + r16) * 32 + quad * 8);
    }
    #pragma unroll
    for (int j = 0; j < 3; ++j) {
      const short8 bvh = *(const short8*)(sBhc + (wn + j * 16 + r16) * 32 + quad * 8);
      const short8 bvl = *(const short8*)(sBlc + (wn + j * 16 + r16) * 32 + quad * 8);
      #pragma unroll
      for (int i = 0; i < 4; ++i) {
        acc[i][j] = __builtin_amdgcn_mfma_f32_16x16x32_bf16(avh[i], bvh, acc[i][j], 0, 0, 0);
        acc[i][j] = __builtin_amdgcn_mfma_f32_16x16x32_bf16(avh[i], bvl, acc[i][j], 0, 0, 0);
        acc[i][j] = __builtin_amdgcn_mfma_f32_16x16x32_bf16(avl[i], bvh, acc[i][j], 0, 0, 0);
      }
    }
    if (kt < 11) {
      castA(nxt);
      __syncthreads();
    }
  }

  #pragma unroll
  for (int j = 0; j < 3; ++j) {
    const int col = wn + j * 16 + r16;
    const float bj = bc[col];
    #pragma unroll
    for (int i = 0; i < 4; ++i) {
      const int mbase = m0 + wm + i * 16 + quad * 4;
      #pragma unroll
      for (int r = 0; r < 4; ++r)
        proj[(size_t)(mbase + r) * 96 + col] = acc[i][j][r] + bj;
    }
  }
}

// -------------------------------------------------------------------------
// Fat kernel: blocks [0,256) proj GEMM, [256,1024) v GEMM. LDS 57344 ->
// 2 blocks/CU, both bodies 2-phase prefetched.
// -------------------------------------------------------------------------
__global__ __launch_bounds__(256)
void fat_kernel(const float* __restrict__ value, const bf16* __restrict__ Wvt,
                const float* __restrict__ bv,    bf16* __restrict__ vB,
                const float* __restrict__ Q,     const bf16* __restrict__ Wch,
                const bf16* __restrict__ Wcl,    const float* __restrict__ bcat,
                float* __restrict__ proj)
{
  __shared__ __align__(16) char smem[57344];
  const int pb = blockIdx.x;
  if (pb < 256) {
    proj_body(smem, pb, Q, Wch, Wcl, bcat, proj);
  } else {
    vgemm_body(smem, pb - 256, value, Wvt, bv, vB);
  }
}

// -------------------------------------------------------------------------
// tail kernel: fused sample + output GEMM. 256 blocks x 512 thr,
// 128 tokens/block.
//  phase 1 (4 quarters of 32 tokens): coords+softmax -> LDS scratch,
//    bilinear gather (softmax wt premultiplied) -> sAgg[128][392] bf16.
//  phase 2: out[128][384] = sAgg @ Wo^T + bo, A read straight from LDS,
//    B double-buffered via global_load_lds, 1 barrier/kstep.
// Saves the 50 MB agg HBM round-trip + one dispatch vs split kernels.
// XCD swizzle: chunk = (raw%8)*32 + raw/8 -> each XCD owns one batch's
// v slice (3.1 MB, L2-resident).
// -------------------------------------------------------------------------
__global__ __launch_bounds__(512)
void tail_kernel(const float* __restrict__ proj, const bf16* __restrict__ v,
                 const bf16* __restrict__ Wot, const float* __restrict__ bo,
                 float* __restrict__ out)
{
  __shared__ __align__(16) char smem[149504];
  bf16* sAgg = (bf16*)smem;                    // [128][392] = 100352 B
  char* aux  = smem + 100352;
  int4*   scoff = (int4*)aux;                  // [32*32] phase-1 scratch
  float4* scw   = (float4*)(aux + 16384);      // [32*32]   (aliases sB)
  char*   sBB   = aux;                         // [2][24576] phase-2 B dbuf

  const int raw   = blockIdx.x;
  const int chunk = (raw & 7) * 32 + (raw >> 3);
  const int m0    = chunk * 128;
  const int b     = m0 >> 12;
  const int l0    = m0 & 4095;
  const int t     = threadIdx.x;

  // ---------------- phase 1: sample ----------------
  for (int qt = 0; qt < 4; ++qt) {
    const int tok0 = qt * 32;
    #pragma unroll
    for (int it = 0; it < 2; ++it) {
      const int task = t + it * 512;          // 0..1023
      const int tl   = task >> 5;             // local token 0..31
      const int pt   = task & 31;             // h*4+p
      const int tok  = tok0 + tl;
      const int l    = l0 + tok;
      const float* pb_ = proj + (size_t)(m0 + tok) * 96;
      const float2 off = *(const float2*)(pb_ + 2 * pt);
      const int h = pt >> 2, p = pt & 3;
      const float4 lg = *(const float4*)(pb_ + 64 + h * 4);
      const float g[4] = {lg.x, lg.y, lg.z, lg.w};
      const float mx = fmaxf(fmaxf(g[0], g[1]), fmaxf(g[2], g[3]));
      float e[4], sum = 0.f;
      #pragma unroll
      for (int jj = 0; jj < 4; ++jj) { e[jj] = expf(g[jj] - mx); sum += e[jj]; }
      const float wt = e[p] / sum;
      const float refx = (float)(l & 63) * (1.0f / 63.0f);
      const float refy = (float)(l >> 6) * (1.0f / 63.0f);
      const float locx = fminf(fmaxf(refx + off.x, 0.f), 1.f);
      const float locy = fminf(fmaxf(refy + off.y, 0.f), 1.f);
      const float ph = locx * 63.0f;          // faithful: component 0 -> row coord
      const float pw = locy * 63.0f;
      const float fy = floorf(ph), fx = floorf(pw);
      const int y0 = (int)fy, x0 = (int)fx;
      const int y1 = min(y0 + 1, 63), x1 = min(x0 + 1, 63);
      const float wy = ph - fy, wx = pw - fx;
      scoff[tl * 32 + pt] = make_int4((y0 * kGW + x0) * kD, (y0 * kGW + x1) * kD,
                                      (y1 * kGW + x0) * kD, (y1 * kGW + x1) * kD);
      scw[tl * 32 + pt] = make_float4(wt * (1.f - wy) * (1.f - wx), wt * (1.f - wy) * wx,
                                      wt * wy * (1.f - wx),         wt * wy * wx);
    }
    __syncthreads();
    #pragma unroll
    for (int it = 0; it < 6; ++it) {
      const int task = t + it * 512;          // 0..3071
      const int tl = task / 96;               // local token 0..31
      const int q  = task - tl * 96;
      const int h  = q / 12;
      const int col = q * 4;                  // = h*48 + (q%12)*4
      const unsigned short* vb = (const unsigned short*)(v + (size_t)b * kL * kD + col);
      float4v acc = (float4v){0.f, 0.f, 0.f, 0.f};
      #pragma unroll
      for (int p = 0; p < 4; ++p) {
        const int4   o = scoff[tl * 32 + h * 4 + p];
        const float4 w = scw  [tl * 32 + h * 4 + p];
        const ushort4 u0 = *(const ushort4*)(vb + o.x);
        const ushort4 u1 = *(const ushort4*)(vb + o.y);
        const ushort4 u2 = *(const ushort4*)(vb + o.z);
        const ushort4 u3 = *(const ushort4*)(vb + o.w);
        acc[0] += w.x * bf16raw2f(u0.x) + w.y * bf16raw2f(u1.x)
                + w.z * bf16raw2f(u2.x) + w.w * bf16raw2f(u3.x);
        acc[1] += w.x * bf16raw2f(u0.y) + w.y * bf16raw2f(u1.y)
                + w.z * bf16raw2f(u2.y) + w.w * bf16raw2f(u3.y);
        acc[2] += w.x * bf16raw2f(u0.z) + w.y * bf16raw2f(u1.z)
                + w.z * bf16raw2f(u2.z) + w.w * bf16raw2f(u3.z);
        acc[3] += w.x * bf16raw2f(u0.w) + w.y * bf16raw2f(u1.w)
                + w.z * bf16raw2f(u2.w) + w.w * bf16raw2f(u3.w);
      }
      ushort4 ou;
      ou.x = (unsigned short)bf16bits(acc[0]);
      ou.y = (unsigned short)bf16bits(acc[1]);
      ou.z = (unsigned short)bf16bits(acc[2]);
      ou.w = (unsigned short)bf16bits(acc[3]);
      *(ushort4*)(sAgg + (size_t)(tok0 + tl) * kAP + col) = ou;
    }
    __syncthreads();   // gather done; scratch reusable / sAgg rows published
  }

  // ---------------- phase 2: out = sAgg @ Wo^T + bo ----------------
  const int lane = t & 63, wave = t >> 6;
  const int r16 = lane & 15, quad = lane >> 4;
  const int wm = (wave >> 2) * 64;            // 0/64
  const int wn = (wave & 3) * 96;             // 0/96/192/288
  float4v acc2[4][6];
  #pragma unroll
  for (int i = 0; i < 4; ++i)
    #pragma unroll
    for (int j = 0; j < 6; ++j) acc2[i][j] = (float4v){0.f, 0.f, 0.f, 0.f};

  #pragma unroll
  for (int r = 0; r < 3; ++r) {
    const int c = t + r * 512;                // 0..1535: row=c>>2 (0..383), kc=c&3
    load_lds_16(Wot + (size_t)(c >> 2) * kD + (c & 3) * 8, sBB + c * 16);
  }
  __syncthreads();

  for (int kt = 0; kt < 12; ++kt) {
    const int cur = kt & 1;
    if (kt < 11) {
      const int k0n = (kt + 1) * 32;
      #pragma unroll
      for (int r = 0; r < 3; ++r) {
        const int c = t + r * 512;
        load_lds_16(Wot + (size_t)(c >> 2) * kD + k0n + (c & 3) * 8,
                    sBB + (cur ^ 1) * 24576 + c * 16);
      }
    }
    const int k0 = kt * 32;
    const bf16* sBc = (const bf16*)(sBB + cur * 24576);
    short8 av[4];
    #pragma unroll
    for (int i = 0; i < 4; ++i)
      av[i] = *(const short8*)(sAgg + (size_t)(wm + i * 16 + r16) * kAP + k0 + quad * 8);
    #pragma unroll
    for (int j = 0; j < 6; ++j) {
      const short8 bvj = *(const short8*)(sBc + (wn + j * 16 + r16) * 32 + quad * 8);
      #pragma unroll
      for (int i = 0; i < 4; ++i)
        acc2[i][j] = __builtin_amdgcn_mfma_f32_16x16x32_bf16(av[i], bvj, acc2[i][j], 0, 0, 0);
    }
    if (kt < 11) __syncthreads();
  }

  #pragma unroll
  for (int j = 0; j < 6; ++j) {
    const int col = wn + j * 16 + r16;
    const float bj = bo[col];
    #pragma unroll
    for (int i = 0; i < 4; ++i) {
      const int mb = m0 + wm + i * 16 + quad * 4;
      #pragma unroll
      for (int r = 0; r < 4; ++r)
        out[(size_t)(mb + r) * kD + col] = acc2[i][j][r] + bj;
    }
  }
}

extern "C" void kernel_launch(void* const* d_in, const int* in_sizes, int n_in,
                              void* d_out, int out_size, void* d_ws, size_t ws_size,
                              hipStream_t stream)
{
  const float* query = (const float*)d_in[0];
  const float* value = (const float*)d_in[2];
  const float* Wv    = (const float*)d_in[7];
  const float* bv    = (const float*)d_in[8];
  const float* Woff  = (const float*)d_in[9];
  const float* boff  = (const float*)d_in[10];
  const float* Wwt   = (const float*)d_in[11];
  const float* bwt   = (const float*)d_in[12];
  const float* Wo    = (const float*)d_in[13];
  const float* bo    = (const float*)d_in[14];
  float* out = (float*)d_out;

  char* ws = (char*)d_ws;
  bf16*  Wvt  = (bf16*)(ws + oWvt);
  bf16*  Wot  = (bf16*)(ws + oWot);
  bf16*  Wch  = (bf16*)(ws + oWch);
  bf16*  Wcl  = (bf16*)(ws + oWcl);
  float* bcat = (float*)(ws + oBcat);
  bf16*  vB   = (bf16*)(ws + oVB);
  float* proj = (float*)(ws + oProj);

  const size_t prepN = nW + nW + nWcat + 96;
  prep_kernel<<<dim3((unsigned)((prepN + 255) / 256)), 256, 0, stream>>>(
      Wv, Wo, Woff, Wwt, boff, bwt, Wvt, Wot, Wch, Wcl, bcat);

  // vGEMM (768 blocks) + proj GEMM (256 blocks), both 2-phase prefetched
  fat_kernel<<<dim3(256 + 768), 256, 0, stream>>>(
      value, Wvt, bv, vB, query, Wch, Wcl, bcat, proj);

  // fused: coords + softmax + bilinear gather -> LDS agg -> out GEMM
  tail_kernel<<<dim3(256), 512, 0, stream>>>(proj, vB, Wot, bo, out);
}